// Round 9
// baseline (306.220 us; speedup 1.0000x reference)
//
#include <hip/hip_runtime.h>
#include <math.h>

#define N_NODES  30000
#define N_EDGES  240000
#define E_TOT    270000   // N_EDGES + N_NODES self loops
#define N_GRAPHS 300
#define NCH      118      // cdiv(N_NODES, 256)

typedef _Float16 half8 __attribute__((ext_vector_type(8)));
typedef _Float16 half4 __attribute__((ext_vector_type(4)));
typedef float float4v __attribute__((ext_vector_type(4)));

static inline int cdiv(int a, int b) { return (a + b - 1) / b; }

// async 16B global->LDS (DMA, no VGPR round-trip)
static __device__ __forceinline__ void gload_lds16(const void* g, void* l) {
    __builtin_amdgcn_global_load_lds(
        (const __attribute__((address_space(1))) void*)g,
        (__attribute__((address_space(3))) void*)l, 16, 0, 0);
}

// VALU-only cross-lane add via DPP. CTRL: 0x120|N = row_ror:N.
template<int CTRL>
static __device__ __forceinline__ float dpp_add(float v) {
    int t = __builtin_amdgcn_update_dpp(0, __float_as_int(v), CTRL, 0xF, 0xF, false);
    return v + __int_as_float(t);
}
static __device__ __forceinline__ float red16(float v) {   // 16-lane row sum
    v = dpp_add<0x128>(v);
    v = dpp_add<0x124>(v);
    v = dpp_add<0x122>(v);
    v = dpp_add<0x121>(v);
    return v;
}

// ---------------------------------------------------------------------------
// Weight transpose: OUTPUT-major iteration -> contiguous 2B writes, strided
// 4B reads (absorbed by L2).
// ---------------------------------------------------------------------------
__device__ inline void wp_dev(const float* __restrict__ W, _Float16* __restrict__ Wt,
                              int K, int CO, int gtid, int T) {
    int tot = K * CO;
    for (int i = gtid; i < tot; i += T) {
        int c = i / K, k = i - c * K;          // Wt[i] = Wt[c*K + k]
        Wt[i] = (_Float16)W[(size_t)k * CO + c];
    }
}

// ---------------------------------------------------------------------------
// K1: degree histogram (int4 edge loads; self-loops folded into scan) +
// w1 transposes + input layer (K=5 GEMM).
// ---------------------------------------------------------------------------
__global__ void hist_wprep_input(const int* __restrict__ ei, int* __restrict__ deg,
                                 const float* __restrict__ x, const float* __restrict__ w_in,
                                 const float* __restrict__ b_in, const float* __restrict__ bn_in,
                                 _Float16* __restrict__ a16,
                                 const float* __restrict__ w1l, const float* __restrict__ w1r,
                                 _Float16* __restrict__ t1l, _Float16* __restrict__ t1r) {
    int gtid = blockIdx.x * blockDim.x + threadIdx.x;
    int T = gridDim.x * blockDim.x;
    const int4* dst4 = (const int4*)(ei + N_EDGES);
    for (int e4 = gtid; e4 < N_EDGES / 4; e4 += T) {
        int4 d4 = dst4[e4];
        atomicAdd(&deg[d4.x], 1);
        atomicAdd(&deg[d4.y], 1);
        atomicAdd(&deg[d4.z], 1);
        atomicAdd(&deg[d4.w], 1);
    }
    wp_dev(w1l, t1l, 64, 256, gtid, T);
    wp_dev(w1r, t1r, 64, 256, gtid, T);

    int lane = threadIdx.x & 63;
    int wv = blockIdx.x * (blockDim.x >> 6) + (threadIdx.x >> 6);
    int NW = gridDim.x * (blockDim.x >> 6);
    float g = bn_in[lane], be = bn_in[64 + lane];
    float m = bn_in[128 + lane], va = bn_in[192 + lane];
    float rs = rsqrtf(va + 1e-5f);
    float wcol[5];
#pragma unroll
    for (int ci = 0; ci < 5; ++ci) wcol[ci] = w_in[ci * 64 + lane];
    float bb = b_in[lane];
    for (int n = wv; n < N_NODES; n += NW) {
        float xv = (lane < 5) ? x[n * 5 + lane] : 0.f;
        float acc = bb;
#pragma unroll
        for (int ci = 0; ci < 5; ++ci)
            acc = fmaf(__shfl(xv, ci, 64), wcol[ci], acc);
        acc = g * (acc - m) * rs + be;
        a16[(size_t)n * 64 + lane] = (_Float16)fmaxf(acc, 0.f);
    }
}

// ---------------------------------------------------------------------------
// K2: one-launch scan (row_start) + gstart binary search. deg holds edge-only
// counts; the +1 self loop is applied here (v = deg+1, base += b*256).
// ---------------------------------------------------------------------------
__global__ __launch_bounds__(256)
void scan_all(const int* __restrict__ deg, const int* __restrict__ batch,
              int* __restrict__ row_start, int* __restrict__ gstart) {
    __shared__ int red[256];
    __shared__ int s[256];
    const int b = blockIdx.x, t = threadIdx.x;
    const int4* deg4 = (const int4*)deg;
    int pre = 0;
    for (int i = t; i < b * 64; i += 256) {    // b*256 ints = b*64 int4s
        int4 v4 = deg4[i];
        pre += (v4.x + v4.y) + (v4.z + v4.w);
    }
    red[t] = pre;
    __syncthreads();
    for (int off = 128; off; off >>= 1) {
        if (t < off) red[t] += red[t + off];
        __syncthreads();
    }
    int base = red[0] + b * 256;               // + self loops of prior nodes
    int gid = b * 256 + t;
    int v = (gid < N_NODES) ? deg[gid] + 1 : 0;   // +1 self loop
    s[t] = v;
    __syncthreads();
    for (int off = 1; off < 256; off <<= 1) {
        int u = (t >= off) ? s[t - off] : 0;
        __syncthreads();
        s[t] += u;
        __syncthreads();
    }
    if (gid < N_NODES) row_start[gid] = base + s[t] - v;
    if (b == 0 && t == 0) row_start[N_NODES] = E_TOT;
    if (b == 0) {
        for (int g = t; g <= N_GRAPHS; g += 256) {
            int lo = 0, hi = N_NODES;
            while (lo < hi) {
                int mid = (lo + hi) >> 1;
                if (batch[mid] < g) lo = mid + 1;
                else                hi = mid;
            }
            gstart[g] = lo;
        }
    }
}

// ---------------------------------------------------------------------------
// MFMA f16 pair GEMM. Flat 1-D grid with bijective XCD chunk remap (m204).
// Operand-SWAPPED mfma -> half4 epilogue stores. global_load_lds staging
// with XOR unit-swizzle. SCAT=1 appends blocks doing CSR scatter + deferred
// wt2/wt3 transposes (overlap with this kernel's GEMM blocks).
// ---------------------------------------------------------------------------
template<int K, int COUT, int SCAT>
__global__ __launch_bounds__(256, 4)
void gemm_mfma(const _Float16* __restrict__ A,
               const _Float16* __restrict__ Wtl, const float* __restrict__ bl,
               const _Float16* __restrict__ Wtr, const float* __restrict__ br,
               _Float16* __restrict__ outl, _Float16* __restrict__ outr,
               const int* __restrict__ ei, const int* __restrict__ row_start,
               int* __restrict__ cnt, int* __restrict__ esrc, int N,
               const float* __restrict__ w2l, const float* __restrict__ w2r,
               const float* __restrict__ w3l, const float* __restrict__ w3r,
               _Float16* __restrict__ t2l, _Float16* __restrict__ t2r,
               _Float16* __restrict__ t3l, _Float16* __restrict__ t3r) {
    constexpr int BM = 128, BN = 128, BK = 64;
    constexpr int CSL = COUT / BN > 0 ? COUT / BN : 1;
    constexpr int NS  = 2 * CSL;
    const int NT  = (N + BM - 1) / BM;
    const int nwg = NT * NS;
    const int id  = blockIdx.x;
    if (SCAT && id >= nwg) {                    // scatter + deferred transposes
        int gtid = (id - nwg) * blockDim.x + threadIdx.x;
        int T = (gridDim.x - nwg) * blockDim.x;
        for (int e = gtid; e < E_TOT; e += T) {
            int s, d;
            if (e < N_EDGES) { s = ei[e]; d = ei[N_EDGES + e]; }
            else             { s = e - N_EDGES; d = s; }
            int slot = row_start[d] + atomicAdd(&cnt[d], 1);
            esrc[slot] = s;
        }
        wp_dev(w2l, t2l, 256, 256, gtid, T);
        wp_dev(w2r, t2r, 256, 256, gtid, T);
        wp_dev(w3l, t3l, 256, 128, gtid, T);
        wp_dev(w3r, t3r, 256, 128, gtid, T);
        return;
    }
    // bijective XCD chunk remap, slice-fastest within chunk
    const int q = nwg >> 3, r = nwg & 7, xcd = id & 7, kk_ = id >> 3;
    const int rm = (xcd < r ? xcd * (q + 1) : r * (q + 1) + (xcd - r) * q) + kk_;
    const int tile = rm / NS, slice = rm % NS;

    __shared__ __attribute__((aligned(16))) _Float16 As[BM * BK];
    __shared__ __attribute__((aligned(16))) _Float16 Bs[BN * BK];
    const int tid  = threadIdx.x;
    const int wave = tid >> 6;
    const int lane = tid & 63;
    const int l15  = lane & 15;
    const int lq   = lane >> 4;
    const int n0   = tile * BM;
    const int sel  = slice / CSL;
    const int col0 = (slice % CSL) * BN;
    const _Float16* Wt = sel ? Wtr : Wtl;
    const float* bias  = sel ? br : bl;
    _Float16* out      = sel ? outr : outl;

    // staging coords: idx = p*256+tid -> row = p*32 + (tid>>3), unit = tid&7
    const int r0 = tid >> 3;
    const int us = (tid & 7) ^ (r0 & 7);       // swizzled source unit (involution)

    float4v acc[2][8];
#pragma unroll
    for (int mi = 0; mi < 2; ++mi)
#pragma unroll
        for (int nt = 0; nt < 8; ++nt)
#pragma unroll
            for (int r2 = 0; r2 < 4; ++r2) acc[mi][nt][r2] = 0.f;

    for (int kt = 0; kt < K; kt += BK) {
#pragma unroll
        for (int p = 0; p < 4; ++p) {
            int row = p * 32 + r0;
            int gn  = n0 + row;
            if (gn >= N) gn = 0;               // clamp: rows >= N never written back
            gload_lds16(A + (size_t)gn * K + kt + us * 8, As + (p * 256 + tid) * 8);
        }
#pragma unroll
        for (int p = 0; p < 4; ++p) {
            int row = p * 32 + r0;
            gload_lds16(Wt + (size_t)(col0 + row) * K + kt + us * 8, Bs + (p * 256 + tid) * 8);
        }
        __syncthreads();                        // drains vmcnt(0) -> tiles ready
#pragma unroll
        for (int kk = 0; kk < BK; kk += 32) {
            const int sw = (lq + (kk >> 3)) ^ (l15 & 7);   // read-side swizzle
            half8 af0 = *(const half8*)(As + (wave * 32 + l15) * BK + sw * 8);
            half8 af1 = *(const half8*)(As + (wave * 32 + 16 + l15) * BK + sw * 8);
#pragma unroll
            for (int nt = 0; nt < 8; ++nt) {
                half8 bf = *(const half8*)(Bs + (nt * 16 + l15) * BK + sw * 8);
                // swapped operands: D[i=col][j=node], j = lane&15, i = lq*4+reg
                acc[0][nt] = __builtin_amdgcn_mfma_f32_16x16x32_f16(bf, af0, acc[0][nt], 0, 0, 0);
                acc[1][nt] = __builtin_amdgcn_mfma_f32_16x16x32_f16(bf, af1, acc[1][nt], 0, 0, 0);
            }
        }
        __syncthreads();
    }
    // epilogue: per lane, node-row = l15-block, 4 consecutive cols in regs
#pragma unroll
    for (int mi = 0; mi < 2; ++mi) {
        int row = n0 + wave * 32 + mi * 16 + l15;
        if (row < N) {
#pragma unroll
            for (int nt = 0; nt < 8; ++nt) {
                int col = col0 + nt * 16 + lq * 4;
                float4v bv = *(const float4v*)(bias + col);
                half4 hv;
#pragma unroll
                for (int r2 = 0; r2 < 4; ++r2)
                    hv[r2] = (_Float16)(acc[mi][nt][r2] + bv[r2]);
                *(half4*)(out + (size_t)row * COUT + col) = hv;
            }
        }
    }
}

// ---------------------------------------------------------------------------
// GATv2 gather (H=4): wave per node, 4-edge slots, unroll 2 (proven form).
// __launch_bounds__(256,6): cap VGPR at 85 -> 6 waves/SIMD for latency hiding
// (gathers are latency-bound; this is the round's A/B lever).
// leaky_relu(v) == fmaxf(v, 0.2v). NO max-subtraction. DPP red16.
// ---------------------------------------------------------------------------
template<typename TOUT>
__global__ __launch_bounds__(256, 6)
void gat_gather4(const _Float16* __restrict__ xl, const _Float16* __restrict__ xr,
                 const int* __restrict__ row_start, const int* __restrict__ esrc,
                 const float* __restrict__ att, const float* __restrict__ gbias,
                 const float* __restrict__ bnp, TOUT* __restrict__ out) {
    constexpr int HC = 256, PER = 4;
    int node = (blockIdx.x * blockDim.x + threadIdx.x) >> 6;
    int lane = threadIdx.x & 63;
    if (node >= N_NODES) return;
    const int base = lane * PER;

    float rr[PER], av[PER], acc[PER];
    {
        half4 rv = *(const half4*)(xr + (size_t)node * HC + base);
#pragma unroll
        for (int k = 0; k < PER; ++k) rr[k] = (float)rv[k];
        *(float4v*)av = *(const float4v*)(att + base);
    }
#pragma unroll
    for (int k = 0; k < PER; ++k) acc[k] = 0.f;

    float l = 0.f;
    const int j0 = row_start[node], j1 = row_start[node + 1];
    for (int jc = j0; jc < j1; jc += 64) {
        int nedge = min(64, j1 - jc);
        int ev = (jc + lane < j1) ? esrc[jc + lane] : 0;
#pragma unroll 2
        for (int jj = 0; jj < nedge; jj += 4) {
            int s[4];
            bool val[4];
#pragma unroll
            for (int u = 0; u < 4; ++u) {
                int idx = jj + u;
                val[u] = idx < nedge;
                s[u] = __shfl(ev, val[u] ? idx : jj, 64);
            }
            float xs[4][PER];
#pragma unroll
            for (int u = 0; u < 4; ++u) {
                half4 xv = *(const half4*)(xl + (size_t)s[u] * HC + base);
#pragma unroll
                for (int k = 0; k < PER; ++k) xs[u][k] = (float)xv[k];
            }
            float pz[4];
#pragma unroll
            for (int u = 0; u < 4; ++u) {
                float pp = 0.f;
#pragma unroll
                for (int k = 0; k < PER; ++k) {
                    float v = xs[u][k] + rr[k];
                    v = fmaxf(v, 0.2f * v);    // leaky_relu, branch-free
                    pp = fmaf(v, av[k], pp);
                }
                pz[u] = red16(pp);             // DPP butterfly within 16 lanes
            }
            float w[4];
#pragma unroll
            for (int u = 0; u < 4; ++u) w[u] = val[u] ? __expf(pz[u]) : 0.f;
            l += (w[0] + w[1]) + (w[2] + w[3]);
#pragma unroll
            for (int k = 0; k < PER; ++k)
                acc[k] += fmaf(w[0], xs[0][k],
                          fmaf(w[1], xs[1][k],
                          fmaf(w[2], xs[2][k], w[3] * xs[3][k])));
        }
    }
    float inv = 1.f / (l + 1e-16f);
    float o[PER];
#pragma unroll
    for (int k = 0; k < PER; ++k) {
        float v = fmaf(acc[k], inv, gbias[base + k]);
        float g  = bnp[base + k], be = bnp[HC + base + k];
        float mm = bnp[2 * HC + base + k], va = bnp[3 * HC + base + k];
        v = g * (v - mm) * rsqrtf(va + 1e-5f) + be;
        o[k] = (v > 0.f) ? v : (__expf(v) - 1.f);
    }
    half4 ov;
#pragma unroll
    for (int k = 0; k < PER; ++k) ov[k] = (_Float16)o[k];
    *(half4*)((_Float16*)out + (size_t)node * HC + base) = ov;
}

// ---------------------------------------------------------------------------
// GATv2 gather (H=1, C=128): DUAL-EDGE wave + unroll 2 (proven form).
// __launch_bounds__(256,6) as above.
// ---------------------------------------------------------------------------
__global__ __launch_bounds__(256, 6)
void gat_gather1(const _Float16* __restrict__ xl, const _Float16* __restrict__ xr,
                 const int* __restrict__ row_start, const int* __restrict__ esrc,
                 const float* __restrict__ att, const float* __restrict__ gbias,
                 const float* __restrict__ bnp, float* __restrict__ out) {
    constexpr int HC = 128, PER = 4;
    int node = (blockIdx.x * blockDim.x + threadIdx.x) >> 6;
    int lane = threadIdx.x & 63;
    if (node >= N_NODES) return;
    const int half = lane >> 5;
    const int base = (lane & 31) * PER;

    float rr[PER], av[PER], acc[PER];
    {
        half4 rv = *(const half4*)(xr + (size_t)node * HC + base);
#pragma unroll
        for (int k = 0; k < PER; ++k) rr[k] = (float)rv[k];
        *(float4v*)av = *(const float4v*)(att + base);
    }
#pragma unroll
    for (int k = 0; k < PER; ++k) acc[k] = 0.f;

    float l = 0.f;
    const int j0 = row_start[node], j1 = row_start[node + 1];
    for (int jc = j0; jc < j1; jc += 64) {
        int nedge = min(64, j1 - jc);
        int ev = (jc + lane < j1) ? esrc[jc + lane] : 0;
#pragma unroll 2
        for (int jj = 0; jj < nedge; jj += 8) {          // 8 edges: 4 per half
            int s[4];
            bool val[4];
#pragma unroll
            for (int u = 0; u < 4; ++u) {
                int idx = jj + 2 * u + half;
                val[u] = idx < nedge;
                s[u] = __shfl(ev, val[u] ? idx : jj, 64);
            }
            float xs[4][PER];
#pragma unroll
            for (int u = 0; u < 4; ++u) {
                half4 xv = *(const half4*)(xl + (size_t)s[u] * HC + base);
#pragma unroll
                for (int k = 0; k < PER; ++k) xs[u][k] = (float)xv[k];
            }
            float pz[4];
#pragma unroll
            for (int u = 0; u < 4; ++u) {
                float pp = 0.f;
#pragma unroll
                for (int k = 0; k < PER; ++k) {
                    float v = xs[u][k] + rr[k];
                    v = fmaxf(v, 0.2f * v);    // leaky_relu, branch-free
                    pp = fmaf(v, av[k], pp);
                }
                pp += __shfl_xor(pp, 16, 64);            // cross-row, in-half
                pz[u] = red16(pp);                       // 4 DPP hops
            }
            float w[4];
#pragma unroll
            for (int u = 0; u < 4; ++u) w[u] = val[u] ? __expf(pz[u]) : 0.f;
            l += (w[0] + w[1]) + (w[2] + w[3]);
#pragma unroll
            for (int k = 0; k < PER; ++k)
                acc[k] += fmaf(w[0], xs[0][k],
                          fmaf(w[1], xs[1][k],
                          fmaf(w[2], xs[2][k], w[3] * xs[3][k])));
        }
    }
    // combine the two halves (disjoint edge sets, same channels)
    l += __shfl_xor(l, 32, 64);
#pragma unroll
    for (int k = 0; k < PER; ++k) acc[k] += __shfl_xor(acc[k], 32, 64);

    if (half == 0) {
        float inv = 1.f / (l + 1e-16f);
        float o[PER];
#pragma unroll
        for (int k = 0; k < PER; ++k) {
            float v = fmaf(acc[k], inv, gbias[base + k]);
            float g  = bnp[base + k], be = bnp[HC + base + k];
            float mm = bnp[2 * HC + base + k], va = bnp[3 * HC + base + k];
            v = g * (v - mm) * rsqrtf(va + 1e-5f) + be;
            o[k] = (v > 0.f) ? v : (__expf(v) - 1.f);
        }
        *(float4v*)(out + (size_t)node * HC + base) = *(float4v*)o;
    }
}

// ---------------------------------------------------------------------------
// K9: fused pooling + classifier, one block (512 threads) per graph.
// float4 node loop (32 threads span a 512B row, 16-way node split).
// ---------------------------------------------------------------------------
__global__ __launch_bounds__(512)
void pool_cls(const float* __restrict__ h, const int* __restrict__ gstart,
              const float* __restrict__ w1, const float* __restrict__ b1,
              const float* __restrict__ bnp,
              const float* __restrict__ w2, const float* __restrict__ b2,
              const float* __restrict__ w3, const float* __restrict__ b3,
              float* __restrict__ out) {
    __shared__ float4v part4[512];             // 8KB: pooling partials
    __shared__ float sg[256];
    __shared__ float sz1[128];
    __shared__ float sz2[64];
    __shared__ float sz3[2];
    float* part = (float*)part4;               // alias for GEMV partials
    int g = blockIdx.x, t = threadIdx.x;
    int a = gstart[g], b = gstart[g + 1];

    // --- mean+max pooling: cq = channel quad (0..31), q16 = node slice
    int cq = t & 31, q16 = t >> 5;             // q16 in 0..15
    float4v sum = {0.f, 0.f, 0.f, 0.f};
    float4v mx  = {-INFINITY, -INFINITY, -INFINITY, -INFINITY};
    for (int i = a + q16; i < b; i += 16) {
        float4v v = *(const float4v*)(h + (size_t)i * 128 + cq * 4);
#pragma unroll
        for (int k = 0; k < 4; ++k) { sum[k] += v[k]; mx[k] = fmaxf(mx[k], v[k]); }
    }
    part4[t] = sum;
    __syncthreads();
    if (t < 32) {
        float4v s = part4[t];
        for (int r = 1; r < 16; ++r) {
            float4v p = part4[r * 32 + t];
#pragma unroll
            for (int k = 0; k < 4; ++k) s[k] += p[k];
        }
        float inv = 1.f / fmaxf((float)(b - a), 1.f);
#pragma unroll
        for (int k = 0; k < 4; ++k) sg[t * 4 + k] = s[k] * inv;
    }
    __syncthreads();
    part4[t] = mx;
    __syncthreads();
    if (t < 32) {
        float4v m = part4[t];
        for (int r = 1; r < 16; ++r) {
            float4v p = part4[r * 32 + t];
#pragma unroll
            for (int k = 0; k < 4; ++k) m[k] = fmaxf(m[k], p[k]);
        }
#pragma unroll
        for (int k = 0; k < 4; ++k) sg[128 + t * 4 + k] = (b > a) ? m[k] : 0.f;
    }
    __syncthreads();

    // --- classifier GEMV chain (proven 512-thread split)
    int c = t & 127, q = t >> 7;               // q in 0..3
    float acc = 0.f;
    for (int i = q * 64; i < q * 64 + 64; ++i) acc += sg[i] * w1[i * 128 + c];
    part[t] = acc;
    __syncthreads();
    if (q == 0) {
        float z = part[c] + part[c + 128] + part[c + 256] + part[c + 384] + b1[c];
        float ga = bnp[c], be = bnp[128 + c], m = bnp[256 + c], va = bnp[384 + c];
        z = ga * (z - m) * rsqrtf(va + 1e-5f) + be;
        sz1[c] = fmaxf(z, 0.f);
    }
    __syncthreads();
    if (t < 128) {
        int o = t & 63, q2 = t >> 6;
        float a2 = 0.f;
        for (int i = q2 * 64; i < q2 * 64 + 64; ++i) a2 += sz1[i] * w2[i * 64 + o];
        part[t] = a2;
    }
    __syncthreads();
    if (t < 64) sz2[t] = fmaxf(part[t] + part[t + 64] + b2[t], 0.f);
    __syncthreads();
    if (t < 2) {
        float a3 = b3[t];
        for (int i = 0; i < 64; ++i) a3 += sz2[i] * w3[i * 2 + t];
        sz3[t] = a3;
    }
    __syncthreads();
    if (t < 2) {
        float mm = fmaxf(sz3[0], sz3[1]);
        float lse = mm + logf(expf(sz3[0] - mm) + expf(sz3[1] - mm));
        out[g * 2 + t] = sz3[t] - lse;
    }
}

// ---------------------------------------------------------------------------
// launch: 1 memset + 9 kernels
// ---------------------------------------------------------------------------
extern "C" void kernel_launch(void* const* d_in, const int* in_sizes, int n_in,
                              void* d_out, int out_size, void* d_ws, size_t ws_size,
                              hipStream_t stream) {
    const float* x       = (const float*)d_in[0];
    const int*   ei      = (const int*)d_in[1];
    const int*   batch   = (const int*)d_in[2];
    const float* w_in    = (const float*)d_in[3];
    const float* b_in    = (const float*)d_in[4];
    const float* bn_in   = (const float*)d_in[5];
    const float* g1_wl   = (const float*)d_in[6];
    const float* g1_bl   = (const float*)d_in[7];
    const float* g1_wr   = (const float*)d_in[8];
    const float* g1_br   = (const float*)d_in[9];
    const float* g1_att  = (const float*)d_in[10];
    const float* g1_bias = (const float*)d_in[11];
    const float* bn1     = (const float*)d_in[12];
    const float* g2_wl   = (const float*)d_in[13];
    const float* g2_bl   = (const float*)d_in[14];
    const float* g2_wr   = (const float*)d_in[15];
    const float* g2_br   = (const float*)d_in[16];
    const float* g2_att  = (const float*)d_in[17];
    const float* g2_bias = (const float*)d_in[18];
    const float* bn2     = (const float*)d_in[19];
    const float* g3_wl   = (const float*)d_in[20];
    const float* g3_bl   = (const float*)d_in[21];
    const float* g3_wr   = (const float*)d_in[22];
    const float* g3_br   = (const float*)d_in[23];
    const float* g3_att  = (const float*)d_in[24];
    const float* g3_bias = (const float*)d_in[25];
    const float* bn3     = (const float*)d_in[26];
    const float* c_w1    = (const float*)d_in[27];
    const float* c_b1    = (const float*)d_in[28];
    const float* c_bn    = (const float*)d_in[29];
    const float* c_w2    = (const float*)d_in[30];
    const float* c_b2    = (const float*)d_in[31];
    const float* c_w3    = (const float*)d_in[32];
    const float* c_b3    = (const float*)d_in[33];
    float* out = (float*)d_out;

    // ---- workspace layout
    const size_t NHC = (size_t)N_NODES * 256;
    _Float16* a16  = (_Float16*)d_ws;
    _Float16* xl16 = a16 + NHC;
    _Float16* xr16 = xl16 + NHC;
    _Float16* wt = xr16 + NHC;
    _Float16* wt1l = wt;            _Float16* wt1r = wt + 16384;
    _Float16* wt2l = wt + 32768;    _Float16* wt2r = wt + 98304;
    _Float16* wt3l = wt + 163840;   _Float16* wt3r = wt + 196608;
    float* fbase = (float*)(wt + 262144);
    float* bufD = fbase;
    int* iw = (int*)(bufD + (size_t)N_NODES * 128);
    int* deg       = iw;            int* cnt    = iw + 30000;   // contiguous pair
    int* row_start = iw + 90128;
    int* esrc      = iw + 120129;
    int* gstart    = iw + 390429;

    const int BT = 256;
    const int NT128 = cdiv(N_NODES, 128);      // 235

    // N0: zero deg+cnt
    hipMemsetAsync(deg, 0, 60000 * sizeof(int), stream);

    // K1: histogram + w1 transpose + input layer
    hist_wprep_input<<<1024, BT, 0, stream>>>(ei, deg, x, w_in, b_in, bn_in, a16,
                                              g1_wl, g1_wr, wt1l, wt1r);
    // K2: row_start scan + gstart binary search
    scan_all<<<NCH, 256, 0, stream>>>(deg, batch, row_start, gstart);

    // K3: GAT layer-1 GEMM + fused CSR scatter + deferred wt2/wt3 transposes
    gemm_mfma<64, 256, 1><<<NT128 * 4 + NT128, 256, 0, stream>>>(
        a16, wt1l, g1_bl, wt1r, g1_br, xl16, xr16, ei, row_start, cnt, esrc, N_NODES,
        g2_wl, g2_wr, g3_wl, g3_wr, wt2l, wt2r, wt3l, wt3r);
    // K4: gather 1
    gat_gather4<_Float16><<<cdiv(N_NODES * 64, BT), BT, 0, stream>>>(
        xl16, xr16, row_start, esrc, g1_att, g1_bias, bn1, a16);

    // K5/K6: GAT layer 2
    gemm_mfma<256, 256, 0><<<NT128 * 4, 256, 0, stream>>>(
        a16, wt2l, g2_bl, wt2r, g2_br, xl16, xr16, nullptr, nullptr, nullptr, nullptr, N_NODES,
        nullptr, nullptr, nullptr, nullptr, nullptr, nullptr, nullptr, nullptr);
    gat_gather4<_Float16><<<cdiv(N_NODES * 64, BT), BT, 0, stream>>>(
        xl16, xr16, row_start, esrc, g2_att, g2_bias, bn2, a16);

    // K7/K8: GAT layer 3 (dual-edge gather emits f32 for pooling)
    gemm_mfma<256, 128, 0><<<NT128 * 2, 256, 0, stream>>>(
        a16, wt3l, g3_bl, wt3r, g3_br, xl16, xr16, nullptr, nullptr, nullptr, nullptr, N_NODES,
        nullptr, nullptr, nullptr, nullptr, nullptr, nullptr, nullptr, nullptr);
    gat_gather1<<<cdiv(N_NODES * 64, BT), BT, 0, stream>>>(
        xl16, xr16, row_start, esrc, g3_att, g3_bias, bn3, bufD);

    // K9: fused pooling + classifier
    pool_cls<<<N_GRAPHS, 512, 0, stream>>>(bufD, gstart, c_w1, c_b1, c_bn,
                                           c_w2, c_b2, c_w3, c_b3, out);
}

// Round 10
// 305.323 us; speedup vs baseline: 1.0029x; 1.0029x over previous
//
#include <hip/hip_runtime.h>
#include <math.h>

#define N_NODES  30000
#define N_EDGES  240000
#define E_TOT    270000   // N_EDGES + N_NODES self loops
#define N_GRAPHS 300
#define NCH      118      // cdiv(N_NODES, 256)

typedef _Float16 half8 __attribute__((ext_vector_type(8)));
typedef _Float16 half4 __attribute__((ext_vector_type(4)));
typedef float float4v __attribute__((ext_vector_type(4)));

static inline int cdiv(int a, int b) { return (a + b - 1) / b; }

// async 16B global->LDS (DMA, no VGPR round-trip)
static __device__ __forceinline__ void gload_lds16(const void* g, void* l) {
    __builtin_amdgcn_global_load_lds(
        (const __attribute__((address_space(1))) void*)g,
        (__attribute__((address_space(3))) void*)l, 16, 0, 0);
}

// VALU-only cross-lane add via DPP. CTRL: 0x120|N = row_ror:N.
template<int CTRL>
static __device__ __forceinline__ float dpp_add(float v) {
    int t = __builtin_amdgcn_update_dpp(0, __float_as_int(v), CTRL, 0xF, 0xF, false);
    return v + __int_as_float(t);
}
static __device__ __forceinline__ float red16(float v) {   // 16-lane row sum
    v = dpp_add<0x128>(v);
    v = dpp_add<0x124>(v);
    v = dpp_add<0x122>(v);
    v = dpp_add<0x121>(v);
    return v;
}

// ---------------------------------------------------------------------------
// Weight transpose: OUTPUT-major iteration -> contiguous 2B writes, strided
// 4B reads (absorbed by L2).
// ---------------------------------------------------------------------------
__device__ inline void wp_dev(const float* __restrict__ W, _Float16* __restrict__ Wt,
                              int K, int CO, int gtid, int T) {
    int tot = K * CO;
    for (int i = gtid; i < tot; i += T) {
        int c = i / K, k = i - c * K;          // Wt[i] = Wt[c*K + k]
        Wt[i] = (_Float16)W[(size_t)k * CO + c];
    }
}

// ---------------------------------------------------------------------------
// K1: degree histogram (int4 edge loads; self-loops folded into scan) +
// w1 transposes + input layer (K=5 GEMM).
// ---------------------------------------------------------------------------
__global__ void hist_wprep_input(const int* __restrict__ ei, int* __restrict__ deg,
                                 const float* __restrict__ x, const float* __restrict__ w_in,
                                 const float* __restrict__ b_in, const float* __restrict__ bn_in,
                                 _Float16* __restrict__ a16,
                                 const float* __restrict__ w1l, const float* __restrict__ w1r,
                                 _Float16* __restrict__ t1l, _Float16* __restrict__ t1r) {
    int gtid = blockIdx.x * blockDim.x + threadIdx.x;
    int T = gridDim.x * blockDim.x;
    const int4* dst4 = (const int4*)(ei + N_EDGES);
    for (int e4 = gtid; e4 < N_EDGES / 4; e4 += T) {
        int4 d4 = dst4[e4];
        atomicAdd(&deg[d4.x], 1);
        atomicAdd(&deg[d4.y], 1);
        atomicAdd(&deg[d4.z], 1);
        atomicAdd(&deg[d4.w], 1);
    }
    wp_dev(w1l, t1l, 64, 256, gtid, T);
    wp_dev(w1r, t1r, 64, 256, gtid, T);

    int lane = threadIdx.x & 63;
    int wv = blockIdx.x * (blockDim.x >> 6) + (threadIdx.x >> 6);
    int NW = gridDim.x * (blockDim.x >> 6);
    float g = bn_in[lane], be = bn_in[64 + lane];
    float m = bn_in[128 + lane], va = bn_in[192 + lane];
    float rs = rsqrtf(va + 1e-5f);
    float wcol[5];
#pragma unroll
    for (int ci = 0; ci < 5; ++ci) wcol[ci] = w_in[ci * 64 + lane];
    float bb = b_in[lane];
    for (int n = wv; n < N_NODES; n += NW) {
        float xv = (lane < 5) ? x[n * 5 + lane] : 0.f;
        float acc = bb;
#pragma unroll
        for (int ci = 0; ci < 5; ++ci)
            acc = fmaf(__shfl(xv, ci, 64), wcol[ci], acc);
        acc = g * (acc - m) * rs + be;
        a16[(size_t)n * 64 + lane] = (_Float16)fmaxf(acc, 0.f);
    }
}

// ---------------------------------------------------------------------------
// K2: one-launch scan (row_start) + gstart binary search. deg holds edge-only
// counts; the +1 self loop is applied here (v = deg+1, base += b*256).
// ---------------------------------------------------------------------------
__global__ __launch_bounds__(256)
void scan_all(const int* __restrict__ deg, const int* __restrict__ batch,
              int* __restrict__ row_start, int* __restrict__ gstart) {
    __shared__ int red[256];
    __shared__ int s[256];
    const int b = blockIdx.x, t = threadIdx.x;
    const int4* deg4 = (const int4*)deg;
    int pre = 0;
    for (int i = t; i < b * 64; i += 256) {    // b*256 ints = b*64 int4s
        int4 v4 = deg4[i];
        pre += (v4.x + v4.y) + (v4.z + v4.w);
    }
    red[t] = pre;
    __syncthreads();
    for (int off = 128; off; off >>= 1) {
        if (t < off) red[t] += red[t + off];
        __syncthreads();
    }
    int base = red[0] + b * 256;               // + self loops of prior nodes
    int gid = b * 256 + t;
    int v = (gid < N_NODES) ? deg[gid] + 1 : 0;   // +1 self loop
    s[t] = v;
    __syncthreads();
    for (int off = 1; off < 256; off <<= 1) {
        int u = (t >= off) ? s[t - off] : 0;
        __syncthreads();
        s[t] += u;
        __syncthreads();
    }
    if (gid < N_NODES) row_start[gid] = base + s[t] - v;
    if (b == 0 && t == 0) row_start[N_NODES] = E_TOT;
    if (b == 0) {
        for (int g = t; g <= N_GRAPHS; g += 256) {
            int lo = 0, hi = N_NODES;
            while (lo < hi) {
                int mid = (lo + hi) >> 1;
                if (batch[mid] < g) lo = mid + 1;
                else                hi = mid;
            }
            gstart[g] = lo;
        }
    }
}

// ---------------------------------------------------------------------------
// MFMA f16 pair GEMM. Flat 1-D grid with bijective XCD chunk remap (m204).
// Operand-SWAPPED mfma -> half4 epilogue stores. global_load_lds staging
// with XOR unit-swizzle. SCAT=1 appends blocks doing CSR scatter + deferred
// wt2/wt3 transposes (overlap with this kernel's GEMM blocks).
// ---------------------------------------------------------------------------
template<int K, int COUT, int SCAT>
__global__ __launch_bounds__(256, 4)
void gemm_mfma(const _Float16* __restrict__ A,
               const _Float16* __restrict__ Wtl, const float* __restrict__ bl,
               const _Float16* __restrict__ Wtr, const float* __restrict__ br,
               _Float16* __restrict__ outl, _Float16* __restrict__ outr,
               const int* __restrict__ ei, const int* __restrict__ row_start,
               int* __restrict__ cnt, int* __restrict__ esrc, int N,
               const float* __restrict__ w2l, const float* __restrict__ w2r,
               const float* __restrict__ w3l, const float* __restrict__ w3r,
               _Float16* __restrict__ t2l, _Float16* __restrict__ t2r,
               _Float16* __restrict__ t3l, _Float16* __restrict__ t3r) {
    constexpr int BM = 128, BN = 128, BK = 64;
    constexpr int CSL = COUT / BN > 0 ? COUT / BN : 1;
    constexpr int NS  = 2 * CSL;
    const int NT  = (N + BM - 1) / BM;
    const int nwg = NT * NS;
    const int id  = blockIdx.x;
    if (SCAT && id >= nwg) {                    // scatter + deferred transposes
        int gtid = (id - nwg) * blockDim.x + threadIdx.x;
        int T = (gridDim.x - nwg) * blockDim.x;
        for (int e = gtid; e < E_TOT; e += T) {
            int s, d;
            if (e < N_EDGES) { s = ei[e]; d = ei[N_EDGES + e]; }
            else             { s = e - N_EDGES; d = s; }
            int slot = row_start[d] + atomicAdd(&cnt[d], 1);
            esrc[slot] = s;
        }
        wp_dev(w2l, t2l, 256, 256, gtid, T);
        wp_dev(w2r, t2r, 256, 256, gtid, T);
        wp_dev(w3l, t3l, 256, 128, gtid, T);
        wp_dev(w3r, t3r, 256, 128, gtid, T);
        return;
    }
    // bijective XCD chunk remap, slice-fastest within chunk
    const int q = nwg >> 3, r = nwg & 7, xcd = id & 7, kk_ = id >> 3;
    const int rm = (xcd < r ? xcd * (q + 1) : r * (q + 1) + (xcd - r) * q) + kk_;
    const int tile = rm / NS, slice = rm % NS;

    __shared__ __attribute__((aligned(16))) _Float16 As[BM * BK];
    __shared__ __attribute__((aligned(16))) _Float16 Bs[BN * BK];
    const int tid  = threadIdx.x;
    const int wave = tid >> 6;
    const int lane = tid & 63;
    const int l15  = lane & 15;
    const int lq   = lane >> 4;
    const int n0   = tile * BM;
    const int sel  = slice / CSL;
    const int col0 = (slice % CSL) * BN;
    const _Float16* Wt = sel ? Wtr : Wtl;
    const float* bias  = sel ? br : bl;
    _Float16* out      = sel ? outr : outl;

    // staging coords: idx = p*256+tid -> row = p*32 + (tid>>3), unit = tid&7
    const int r0 = tid >> 3;
    const int us = (tid & 7) ^ (r0 & 7);       // swizzled source unit (involution)

    float4v acc[2][8];
#pragma unroll
    for (int mi = 0; mi < 2; ++mi)
#pragma unroll
        for (int nt = 0; nt < 8; ++nt)
#pragma unroll
            for (int r2 = 0; r2 < 4; ++r2) acc[mi][nt][r2] = 0.f;

    for (int kt = 0; kt < K; kt += BK) {
#pragma unroll
        for (int p = 0; p < 4; ++p) {
            int row = p * 32 + r0;
            int gn  = n0 + row;
            if (gn >= N) gn = 0;               // clamp: rows >= N never written back
            gload_lds16(A + (size_t)gn * K + kt + us * 8, As + (p * 256 + tid) * 8);
        }
#pragma unroll
        for (int p = 0; p < 4; ++p) {
            int row = p * 32 + r0;
            gload_lds16(Wt + (size_t)(col0 + row) * K + kt + us * 8, Bs + (p * 256 + tid) * 8);
        }
        __syncthreads();                        // drains vmcnt(0) -> tiles ready
#pragma unroll
        for (int kk = 0; kk < BK; kk += 32) {
            const int sw = (lq + (kk >> 3)) ^ (l15 & 7);   // read-side swizzle
            half8 af0 = *(const half8*)(As + (wave * 32 + l15) * BK + sw * 8);
            half8 af1 = *(const half8*)(As + (wave * 32 + 16 + l15) * BK + sw * 8);
#pragma unroll
            for (int nt = 0; nt < 8; ++nt) {
                half8 bf = *(const half8*)(Bs + (nt * 16 + l15) * BK + sw * 8);
                // swapped operands: D[i=col][j=node], j = lane&15, i = lq*4+reg
                acc[0][nt] = __builtin_amdgcn_mfma_f32_16x16x32_f16(bf, af0, acc[0][nt], 0, 0, 0);
                acc[1][nt] = __builtin_amdgcn_mfma_f32_16x16x32_f16(bf, af1, acc[1][nt], 0, 0, 0);
            }
        }
        __syncthreads();
    }
    // epilogue: per lane, node-row = l15-block, 4 consecutive cols in regs
#pragma unroll
    for (int mi = 0; mi < 2; ++mi) {
        int row = n0 + wave * 32 + mi * 16 + l15;
        if (row < N) {
#pragma unroll
            for (int nt = 0; nt < 8; ++nt) {
                int col = col0 + nt * 16 + lq * 4;
                float4v bv = *(const float4v*)(bias + col);
                half4 hv;
#pragma unroll
                for (int r2 = 0; r2 < 4; ++r2)
                    hv[r2] = (_Float16)(acc[mi][nt][r2] + bv[r2]);
                *(half4*)(out + (size_t)row * COUT + col) = hv;
            }
        }
    }
}

// ---------------------------------------------------------------------------
// GATv2 gather (H=4): wave per node, 4-edge slots, unroll 2 (proven 301.6µs
// form; natural VGPR allocation — the r8 waves/SIMD cap spilled & regressed).
// leaky_relu(v) == fmaxf(v, 0.2v). NO max-subtraction. DPP red16.
// ---------------------------------------------------------------------------
template<typename TOUT>
__global__ __launch_bounds__(256)
void gat_gather4(const _Float16* __restrict__ xl, const _Float16* __restrict__ xr,
                 const int* __restrict__ row_start, const int* __restrict__ esrc,
                 const float* __restrict__ att, const float* __restrict__ gbias,
                 const float* __restrict__ bnp, TOUT* __restrict__ out) {
    constexpr int HC = 256, PER = 4;
    int node = (blockIdx.x * blockDim.x + threadIdx.x) >> 6;
    int lane = threadIdx.x & 63;
    if (node >= N_NODES) return;
    const int base = lane * PER;

    float rr[PER], av[PER], acc[PER];
    {
        half4 rv = *(const half4*)(xr + (size_t)node * HC + base);
#pragma unroll
        for (int k = 0; k < PER; ++k) rr[k] = (float)rv[k];
        *(float4v*)av = *(const float4v*)(att + base);
    }
#pragma unroll
    for (int k = 0; k < PER; ++k) acc[k] = 0.f;

    float l = 0.f;
    const int j0 = row_start[node], j1 = row_start[node + 1];
    for (int jc = j0; jc < j1; jc += 64) {
        int nedge = min(64, j1 - jc);
        int ev = (jc + lane < j1) ? esrc[jc + lane] : 0;
#pragma unroll 2
        for (int jj = 0; jj < nedge; jj += 4) {
            int s[4];
            bool val[4];
#pragma unroll
            for (int u = 0; u < 4; ++u) {
                int idx = jj + u;
                val[u] = idx < nedge;
                s[u] = __shfl(ev, val[u] ? idx : jj, 64);
            }
            float xs[4][PER];
#pragma unroll
            for (int u = 0; u < 4; ++u) {
                half4 xv = *(const half4*)(xl + (size_t)s[u] * HC + base);
#pragma unroll
                for (int k = 0; k < PER; ++k) xs[u][k] = (float)xv[k];
            }
            float pz[4];
#pragma unroll
            for (int u = 0; u < 4; ++u) {
                float pp = 0.f;
#pragma unroll
                for (int k = 0; k < PER; ++k) {
                    float v = xs[u][k] + rr[k];
                    v = fmaxf(v, 0.2f * v);    // leaky_relu, branch-free
                    pp = fmaf(v, av[k], pp);
                }
                pz[u] = red16(pp);             // DPP butterfly within 16 lanes
            }
            float w[4];
#pragma unroll
            for (int u = 0; u < 4; ++u) w[u] = val[u] ? __expf(pz[u]) : 0.f;
            l += (w[0] + w[1]) + (w[2] + w[3]);
#pragma unroll
            for (int k = 0; k < PER; ++k)
                acc[k] += fmaf(w[0], xs[0][k],
                          fmaf(w[1], xs[1][k],
                          fmaf(w[2], xs[2][k], w[3] * xs[3][k])));
        }
    }
    float inv = 1.f / (l + 1e-16f);
    float o[PER];
#pragma unroll
    for (int k = 0; k < PER; ++k) {
        float v = fmaf(acc[k], inv, gbias[base + k]);
        float g  = bnp[base + k], be = bnp[HC + base + k];
        float mm = bnp[2 * HC + base + k], va = bnp[3 * HC + base + k];
        v = g * (v - mm) * rsqrtf(va + 1e-5f) + be;
        o[k] = (v > 0.f) ? v : (__expf(v) - 1.f);
    }
    half4 ov;
#pragma unroll
    for (int k = 0; k < PER; ++k) ov[k] = (_Float16)o[k];
    *(half4*)((_Float16*)out + (size_t)node * HC + base) = ov;
}

// ---------------------------------------------------------------------------
// GATv2 gather (H=1, C=128): DUAL-EDGE wave + unroll 2 (proven form,
// natural VGPR allocation).
// ---------------------------------------------------------------------------
__global__ __launch_bounds__(256)
void gat_gather1(const _Float16* __restrict__ xl, const _Float16* __restrict__ xr,
                 const int* __restrict__ row_start, const int* __restrict__ esrc,
                 const float* __restrict__ att, const float* __restrict__ gbias,
                 const float* __restrict__ bnp, float* __restrict__ out) {
    constexpr int HC = 128, PER = 4;
    int node = (blockIdx.x * blockDim.x + threadIdx.x) >> 6;
    int lane = threadIdx.x & 63;
    if (node >= N_NODES) return;
    const int half = lane >> 5;
    const int base = (lane & 31) * PER;

    float rr[PER], av[PER], acc[PER];
    {
        half4 rv = *(const half4*)(xr + (size_t)node * HC + base);
#pragma unroll
        for (int k = 0; k < PER; ++k) rr[k] = (float)rv[k];
        *(float4v*)av = *(const float4v*)(att + base);
    }
#pragma unroll
    for (int k = 0; k < PER; ++k) acc[k] = 0.f;

    float l = 0.f;
    const int j0 = row_start[node], j1 = row_start[node + 1];
    for (int jc = j0; jc < j1; jc += 64) {
        int nedge = min(64, j1 - jc);
        int ev = (jc + lane < j1) ? esrc[jc + lane] : 0;
#pragma unroll 2
        for (int jj = 0; jj < nedge; jj += 8) {          // 8 edges: 4 per half
            int s[4];
            bool val[4];
#pragma unroll
            for (int u = 0; u < 4; ++u) {
                int idx = jj + 2 * u + half;
                val[u] = idx < nedge;
                s[u] = __shfl(ev, val[u] ? idx : jj, 64);
            }
            float xs[4][PER];
#pragma unroll
            for (int u = 0; u < 4; ++u) {
                half4 xv = *(const half4*)(xl + (size_t)s[u] * HC + base);
#pragma unroll
                for (int k = 0; k < PER; ++k) xs[u][k] = (float)xv[k];
            }
            float pz[4];
#pragma unroll
            for (int u = 0; u < 4; ++u) {
                float pp = 0.f;
#pragma unroll
                for (int k = 0; k < PER; ++k) {
                    float v = xs[u][k] + rr[k];
                    v = fmaxf(v, 0.2f * v);    // leaky_relu, branch-free
                    pp = fmaf(v, av[k], pp);
                }
                pp += __shfl_xor(pp, 16, 64);            // cross-row, in-half
                pz[u] = red16(pp);                       // 4 DPP hops
            }
            float w[4];
#pragma unroll
            for (int u = 0; u < 4; ++u) w[u] = val[u] ? __expf(pz[u]) : 0.f;
            l += (w[0] + w[1]) + (w[2] + w[3]);
#pragma unroll
            for (int k = 0; k < PER; ++k)
                acc[k] += fmaf(w[0], xs[0][k],
                          fmaf(w[1], xs[1][k],
                          fmaf(w[2], xs[2][k], w[3] * xs[3][k])));
        }
    }
    // combine the two halves (disjoint edge sets, same channels)
    l += __shfl_xor(l, 32, 64);
#pragma unroll
    for (int k = 0; k < PER; ++k) acc[k] += __shfl_xor(acc[k], 32, 64);

    if (half == 0) {
        float inv = 1.f / (l + 1e-16f);
        float o[PER];
#pragma unroll
        for (int k = 0; k < PER; ++k) {
            float v = fmaf(acc[k], inv, gbias[base + k]);
            float g  = bnp[base + k], be = bnp[HC + base + k];
            float mm = bnp[2 * HC + base + k], va = bnp[3 * HC + base + k];
            v = g * (v - mm) * rsqrtf(va + 1e-5f) + be;
            o[k] = (v > 0.f) ? v : (__expf(v) - 1.f);
        }
        *(float4v*)(out + (size_t)node * HC + base) = *(float4v*)o;
    }
}

// ---------------------------------------------------------------------------
// K9: fused pooling + classifier, one block (512 threads) per graph.
// float4 node loop (32 threads span a 512B row, 16-way node split).
// ---------------------------------------------------------------------------
__global__ __launch_bounds__(512)
void pool_cls(const float* __restrict__ h, const int* __restrict__ gstart,
              const float* __restrict__ w1, const float* __restrict__ b1,
              const float* __restrict__ bnp,
              const float* __restrict__ w2, const float* __restrict__ b2,
              const float* __restrict__ w3, const float* __restrict__ b3,
              float* __restrict__ out) {
    __shared__ float4v part4[512];             // 8KB: pooling partials
    __shared__ float sg[256];
    __shared__ float sz1[128];
    __shared__ float sz2[64];
    __shared__ float sz3[2];
    float* part = (float*)part4;               // alias for GEMV partials
    int g = blockIdx.x, t = threadIdx.x;
    int a = gstart[g], b = gstart[g + 1];

    // --- mean+max pooling: cq = channel quad (0..31), q16 = node slice
    int cq = t & 31, q16 = t >> 5;             // q16 in 0..15
    float4v sum = {0.f, 0.f, 0.f, 0.f};
    float4v mx  = {-INFINITY, -INFINITY, -INFINITY, -INFINITY};
    for (int i = a + q16; i < b; i += 16) {
        float4v v = *(const float4v*)(h + (size_t)i * 128 + cq * 4);
#pragma unroll
        for (int k = 0; k < 4; ++k) { sum[k] += v[k]; mx[k] = fmaxf(mx[k], v[k]); }
    }
    part4[t] = sum;
    __syncthreads();
    if (t < 32) {
        float4v s = part4[t];
        for (int r = 1; r < 16; ++r) {
            float4v p = part4[r * 32 + t];
#pragma unroll
            for (int k = 0; k < 4; ++k) s[k] += p[k];
        }
        float inv = 1.f / fmaxf((float)(b - a), 1.f);
#pragma unroll
        for (int k = 0; k < 4; ++k) sg[t * 4 + k] = s[k] * inv;
    }
    __syncthreads();
    part4[t] = mx;
    __syncthreads();
    if (t < 32) {
        float4v m = part4[t];
        for (int r = 1; r < 16; ++r) {
            float4v p = part4[r * 32 + t];
#pragma unroll
            for (int k = 0; k < 4; ++k) m[k] = fmaxf(m[k], p[k]);
        }
#pragma unroll
        for (int k = 0; k < 4; ++k) sg[128 + t * 4 + k] = (b > a) ? m[k] : 0.f;
    }
    __syncthreads();

    // --- classifier GEMV chain (proven 512-thread split)
    int c = t & 127, q = t >> 7;               // q in 0..3
    float acc = 0.f;
    for (int i = q * 64; i < q * 64 + 64; ++i) acc += sg[i] * w1[i * 128 + c];
    part[t] = acc;
    __syncthreads();
    if (q == 0) {
        float z = part[c] + part[c + 128] + part[c + 256] + part[c + 384] + b1[c];
        float ga = bnp[c], be = bnp[128 + c], m = bnp[256 + c], va = bnp[384 + c];
        z = ga * (z - m) * rsqrtf(va + 1e-5f) + be;
        sz1[c] = fmaxf(z, 0.f);
    }
    __syncthreads();
    if (t < 128) {
        int o = t & 63, q2 = t >> 6;
        float a2 = 0.f;
        for (int i = q2 * 64; i < q2 * 64 + 64; ++i) a2 += sz1[i] * w2[i * 64 + o];
        part[t] = a2;
    }
    __syncthreads();
    if (t < 64) sz2[t] = fmaxf(part[t] + part[t + 64] + b2[t], 0.f);
    __syncthreads();
    if (t < 2) {
        float a3 = b3[t];
        for (int i = 0; i < 64; ++i) a3 += sz2[i] * w3[i * 2 + t];
        sz3[t] = a3;
    }
    __syncthreads();
    if (t < 2) {
        float mm = fmaxf(sz3[0], sz3[1]);
        float lse = mm + logf(expf(sz3[0] - mm) + expf(sz3[1] - mm));
        out[g * 2 + t] = sz3[t] - lse;
    }
}

// ---------------------------------------------------------------------------
// launch: 1 memset + 9 kernels
// ---------------------------------------------------------------------------
extern "C" void kernel_launch(void* const* d_in, const int* in_sizes, int n_in,
                              void* d_out, int out_size, void* d_ws, size_t ws_size,
                              hipStream_t stream) {
    const float* x       = (const float*)d_in[0];
    const int*   ei      = (const int*)d_in[1];
    const int*   batch   = (const int*)d_in[2];
    const float* w_in    = (const float*)d_in[3];
    const float* b_in    = (const float*)d_in[4];
    const float* bn_in   = (const float*)d_in[5];
    const float* g1_wl   = (const float*)d_in[6];
    const float* g1_bl   = (const float*)d_in[7];
    const float* g1_wr   = (const float*)d_in[8];
    const float* g1_br   = (const float*)d_in[9];
    const float* g1_att  = (const float*)d_in[10];
    const float* g1_bias = (const float*)d_in[11];
    const float* bn1     = (const float*)d_in[12];
    const float* g2_wl   = (const float*)d_in[13];
    const float* g2_bl   = (const float*)d_in[14];
    const float* g2_wr   = (const float*)d_in[15];
    const float* g2_br   = (const float*)d_in[16];
    const float* g2_att  = (const float*)d_in[17];
    const float* g2_bias = (const float*)d_in[18];
    const float* bn2     = (const float*)d_in[19];
    const float* g3_wl   = (const float*)d_in[20];
    const float* g3_bl   = (const float*)d_in[21];
    const float* g3_wr   = (const float*)d_in[22];
    const float* g3_br   = (const float*)d_in[23];
    const float* g3_att  = (const float*)d_in[24];
    const float* g3_bias = (const float*)d_in[25];
    const float* bn3     = (const float*)d_in[26];
    const float* c_w1    = (const float*)d_in[27];
    const float* c_b1    = (const float*)d_in[28];
    const float* c_bn    = (const float*)d_in[29];
    const float* c_w2    = (const float*)d_in[30];
    const float* c_b2    = (const float*)d_in[31];
    const float* c_w3    = (const float*)d_in[32];
    const float* c_b3    = (const float*)d_in[33];
    float* out = (float*)d_out;

    // ---- workspace layout
    const size_t NHC = (size_t)N_NODES * 256;
    _Float16* a16  = (_Float16*)d_ws;
    _Float16* xl16 = a16 + NHC;
    _Float16* xr16 = xl16 + NHC;
    _Float16* wt = xr16 + NHC;
    _Float16* wt1l = wt;            _Float16* wt1r = wt + 16384;
    _Float16* wt2l = wt + 32768;    _Float16* wt2r = wt + 98304;
    _Float16* wt3l = wt + 163840;   _Float16* wt3r = wt + 196608;
    float* fbase = (float*)(wt + 262144);
    float* bufD = fbase;
    int* iw = (int*)(bufD + (size_t)N_NODES * 128);
    int* deg       = iw;            int* cnt    = iw + 30000;   // contiguous pair
    int* row_start = iw + 90128;
    int* esrc      = iw + 120129;
    int* gstart    = iw + 390429;

    const int BT = 256;
    const int NT128 = cdiv(N_NODES, 128);      // 235

    // N0: zero deg+cnt
    hipMemsetAsync(deg, 0, 60000 * sizeof(int), stream);

    // K1: histogram + w1 transpose + input layer
    hist_wprep_input<<<1024, BT, 0, stream>>>(ei, deg, x, w_in, b_in, bn_in, a16,
                                              g1_wl, g1_wr, wt1l, wt1r);
    // K2: row_start scan + gstart binary search
    scan_all<<<NCH, 256, 0, stream>>>(deg, batch, row_start, gstart);

    // K3: GAT layer-1 GEMM + fused CSR scatter + deferred wt2/wt3 transposes
    gemm_mfma<64, 256, 1><<<NT128 * 4 + NT128, 256, 0, stream>>>(
        a16, wt1l, g1_bl, wt1r, g1_br, xl16, xr16, ei, row_start, cnt, esrc, N_NODES,
        g2_wl, g2_wr, g3_wl, g3_wr, wt2l, wt2r, wt3l, wt3r);
    // K4: gather 1
    gat_gather4<_Float16><<<cdiv(N_NODES * 64, BT), BT, 0, stream>>>(
        xl16, xr16, row_start, esrc, g1_att, g1_bias, bn1, a16);

    // K5/K6: GAT layer 2
    gemm_mfma<256, 256, 0><<<NT128 * 4, 256, 0, stream>>>(
        a16, wt2l, g2_bl, wt2r, g2_br, xl16, xr16, nullptr, nullptr, nullptr, nullptr, N_NODES,
        nullptr, nullptr, nullptr, nullptr, nullptr, nullptr, nullptr, nullptr);
    gat_gather4<_Float16><<<cdiv(N_NODES * 64, BT), BT, 0, stream>>>(
        xl16, xr16, row_start, esrc, g2_att, g2_bias, bn2, a16);

    // K7/K8: GAT layer 3 (dual-edge gather emits f32 for pooling)
    gemm_mfma<256, 128, 0><<<NT128 * 2, 256, 0, stream>>>(
        a16, wt3l, g3_bl, wt3r, g3_br, xl16, xr16, nullptr, nullptr, nullptr, nullptr, N_NODES,
        nullptr, nullptr, nullptr, nullptr, nullptr, nullptr, nullptr, nullptr);
    gat_gather1<<<cdiv(N_NODES * 64, BT), BT, 0, stream>>>(
        xl16, xr16, row_start, esrc, g3_att, g3_bias, bn3, bufD);

    // K9: fused pooling + classifier
    pool_cls<<<N_GRAPHS, 512, 0, stream>>>(bufD, gstart, c_w1, c_b1, c_bn,
                                           c_w2, c_b2, c_w3, c_b3, out);
}

// Round 11
// 301.321 us; speedup vs baseline: 1.0163x; 1.0133x over previous
//
#include <hip/hip_runtime.h>
#include <math.h>

#define N_NODES  30000
#define N_EDGES  240000
#define E_TOT    270000   // N_EDGES + N_NODES self loops
#define N_GRAPHS 300
#define NCH      118      // cdiv(N_NODES, 256)

typedef _Float16 half8 __attribute__((ext_vector_type(8)));
typedef _Float16 half4 __attribute__((ext_vector_type(4)));
typedef float float4v __attribute__((ext_vector_type(4)));

static inline int cdiv(int a, int b) { return (a + b - 1) / b; }

// async 16B global->LDS (DMA, no VGPR round-trip)
static __device__ __forceinline__ void gload_lds16(const void* g, void* l) {
    __builtin_amdgcn_global_load_lds(
        (const __attribute__((address_space(1))) void*)g,
        (__attribute__((address_space(3))) void*)l, 16, 0, 0);
}

// VALU-only cross-lane add via DPP. CTRL: 0x120|N = row_ror:N.
template<int CTRL>
static __device__ __forceinline__ float dpp_add(float v) {
    int t = __builtin_amdgcn_update_dpp(0, __float_as_int(v), CTRL, 0xF, 0xF, false);
    return v + __int_as_float(t);
}
static __device__ __forceinline__ float red16(float v) {   // 16-lane row sum
    v = dpp_add<0x128>(v);
    v = dpp_add<0x124>(v);
    v = dpp_add<0x122>(v);
    v = dpp_add<0x121>(v);
    return v;
}

// ---------------------------------------------------------------------------
// Weight transpose: OUTPUT-major iteration -> contiguous 2B writes, strided
// 4B reads (absorbed by L2). K/CO are compile-time at every call site.
// ---------------------------------------------------------------------------
__device__ inline void wp_dev(const float* __restrict__ W, _Float16* __restrict__ Wt,
                              int K, int CO, int gtid, int T) {
    int tot = K * CO;
    for (int i = gtid; i < tot; i += T) {
        int c = i / K, k = i - c * K;          // Wt[i] = Wt[c*K + k]
        Wt[i] = (_Float16)W[(size_t)k * CO + c];
    }
}

// ---------------------------------------------------------------------------
// K1: degree histogram + w1 transposes + input layer (K=5 GEMM).
// (wt2/wt3 transposes live in K3's scatter slice: overlapped with L1 GEMM.)
// ---------------------------------------------------------------------------
__global__ void hist_wprep_input(const int* __restrict__ ei, int* __restrict__ deg,
                                 const float* __restrict__ x, const float* __restrict__ w_in,
                                 const float* __restrict__ b_in, const float* __restrict__ bn_in,
                                 _Float16* __restrict__ a16,
                                 const float* __restrict__ w1l, const float* __restrict__ w1r,
                                 _Float16* __restrict__ t1l, _Float16* __restrict__ t1r) {
    int gtid = blockIdx.x * blockDim.x + threadIdx.x;
    int T = gridDim.x * blockDim.x;
    for (int e = gtid; e < E_TOT; e += T) {
        int d = (e < N_EDGES) ? ei[N_EDGES + e] : e - N_EDGES;
        atomicAdd(&deg[d], 1);
    }
    wp_dev(w1l, t1l, 64, 256, gtid, T);
    wp_dev(w1r, t1r, 64, 256, gtid, T);

    int lane = threadIdx.x & 63;
    int wv = blockIdx.x * (blockDim.x >> 6) + (threadIdx.x >> 6);
    int NW = gridDim.x * (blockDim.x >> 6);
    float g = bn_in[lane], be = bn_in[64 + lane];
    float m = bn_in[128 + lane], va = bn_in[192 + lane];
    float rs = rsqrtf(va + 1e-5f);
    float wcol[5];
#pragma unroll
    for (int ci = 0; ci < 5; ++ci) wcol[ci] = w_in[ci * 64 + lane];
    float bb = b_in[lane];
    for (int n = wv; n < N_NODES; n += NW) {
        float xv = (lane < 5) ? x[n * 5 + lane] : 0.f;
        float acc = bb;
#pragma unroll
        for (int ci = 0; ci < 5; ++ci)
            acc = fmaf(__shfl(xv, ci, 64), wcol[ci], acc);
        acc = g * (acc - m) * rs + be;
        a16[(size_t)n * 64 + lane] = (_Float16)fmaxf(acc, 0.f);
    }
}

// ---------------------------------------------------------------------------
// K2: one-launch scan (row_start) + gstart binary search. Prefix sums read
// deg as int4 (4x fewer iterations on the critical straggler block).
// ---------------------------------------------------------------------------
__global__ __launch_bounds__(256)
void scan_all(const int* __restrict__ deg, const int* __restrict__ batch,
              int* __restrict__ row_start, int* __restrict__ gstart) {
    __shared__ int red[256];
    __shared__ int s[256];
    const int b = blockIdx.x, t = threadIdx.x;
    const int4* deg4 = (const int4*)deg;
    int pre = 0;
    for (int i = t; i < b * 64; i += 256) {    // b*256 ints = b*64 int4s
        int4 v4 = deg4[i];
        pre += (v4.x + v4.y) + (v4.z + v4.w);
    }
    red[t] = pre;
    __syncthreads();
    for (int off = 128; off; off >>= 1) {
        if (t < off) red[t] += red[t + off];
        __syncthreads();
    }
    int base = red[0];
    int gid = b * 256 + t;
    int v = (gid < N_NODES) ? deg[gid] : 0;
    s[t] = v;
    __syncthreads();
    for (int off = 1; off < 256; off <<= 1) {
        int u = (t >= off) ? s[t - off] : 0;
        __syncthreads();
        s[t] += u;
        __syncthreads();
    }
    if (gid < N_NODES) row_start[gid] = base + s[t] - v;
    if (b == 0 && t == 0) row_start[N_NODES] = E_TOT;
    if (b == 0) {
        for (int g = t; g <= N_GRAPHS; g += 256) {
            int lo = 0, hi = N_NODES;
            while (lo < hi) {
                int mid = (lo + hi) >> 1;
                if (batch[mid] < g) lo = mid + 1;
                else                hi = mid;
            }
            gstart[g] = lo;
        }
    }
}

// ---------------------------------------------------------------------------
// MFMA f16 pair GEMM. Flat 1-D grid with bijective XCD chunk remap (m204):
// same-tile slices become consecutive ON THE SAME XCD -> A-tile L2 hits.
// Operand-SWAPPED mfma: D = Wt_tile * A_tile^T puts node-rows in lane&15 and
// 4 consecutive out-cols in the acc regs -> half4 (8B) epilogue stores.
// global_load_lds staging with XOR unit-swizzle (both-sides involution).
// SCAT=1 appends blocks performing the CSR scatter + the wt2/wt3 transposes
// (needed only by later layers; overlaps with this kernel's GEMM blocks).
// ---------------------------------------------------------------------------
template<int K, int COUT, int SCAT>
__global__ __launch_bounds__(256, 4)
void gemm_mfma(const _Float16* __restrict__ A,
               const _Float16* __restrict__ Wtl, const float* __restrict__ bl,
               const _Float16* __restrict__ Wtr, const float* __restrict__ br,
               _Float16* __restrict__ outl, _Float16* __restrict__ outr,
               const int* __restrict__ ei, const int* __restrict__ row_start,
               int* __restrict__ cnt, int* __restrict__ esrc, int N,
               const float* __restrict__ w2l, const float* __restrict__ w2r,
               const float* __restrict__ w3l, const float* __restrict__ w3r,
               _Float16* __restrict__ t2l, _Float16* __restrict__ t2r,
               _Float16* __restrict__ t3l, _Float16* __restrict__ t3r) {
    constexpr int BM = 128, BN = 128, BK = 64;
    constexpr int CSL = COUT / BN > 0 ? COUT / BN : 1;
    constexpr int NS  = 2 * CSL;
    const int NT  = (N + BM - 1) / BM;
    const int nwg = NT * NS;
    const int id  = blockIdx.x;
    if (SCAT && id >= nwg) {                    // scatter + deferred transposes
        int gtid = (id - nwg) * blockDim.x + threadIdx.x;
        int T = (gridDim.x - nwg) * blockDim.x;
        for (int e = gtid; e < E_TOT; e += T) {
            int s, d;
            if (e < N_EDGES) { s = ei[e]; d = ei[N_EDGES + e]; }
            else             { s = e - N_EDGES; d = s; }
            int slot = row_start[d] + atomicAdd(&cnt[d], 1);
            esrc[slot] = s;
        }
        wp_dev(w2l, t2l, 256, 256, gtid, T);
        wp_dev(w2r, t2r, 256, 256, gtid, T);
        wp_dev(w3l, t3l, 256, 128, gtid, T);
        wp_dev(w3r, t3r, 256, 128, gtid, T);
        return;
    }
    // bijective XCD chunk remap, slice-fastest within chunk
    const int q = nwg >> 3, r = nwg & 7, xcd = id & 7, kk_ = id >> 3;
    const int rm = (xcd < r ? xcd * (q + 1) : r * (q + 1) + (xcd - r) * q) + kk_;
    const int tile = rm / NS, slice = rm % NS;

    __shared__ __attribute__((aligned(16))) _Float16 As[BM * BK];
    __shared__ __attribute__((aligned(16))) _Float16 Bs[BN * BK];
    const int tid  = threadIdx.x;
    const int wave = tid >> 6;
    const int lane = tid & 63;
    const int l15  = lane & 15;
    const int lq   = lane >> 4;
    const int n0   = tile * BM;
    const int sel  = slice / CSL;
    const int col0 = (slice % CSL) * BN;
    const _Float16* Wt = sel ? Wtr : Wtl;
    const float* bias  = sel ? br : bl;
    _Float16* out      = sel ? outr : outl;

    // staging coords: idx = p*256+tid -> row = p*32 + (tid>>3), unit = tid&7
    const int r0 = tid >> 3;
    const int us = (tid & 7) ^ (r0 & 7);       // swizzled source unit (involution)

    float4v acc[2][8];
#pragma unroll
    for (int mi = 0; mi < 2; ++mi)
#pragma unroll
        for (int nt = 0; nt < 8; ++nt)
#pragma unroll
            for (int r2 = 0; r2 < 4; ++r2) acc[mi][nt][r2] = 0.f;

    for (int kt = 0; kt < K; kt += BK) {
#pragma unroll
        for (int p = 0; p < 4; ++p) {
            int row = p * 32 + r0;
            int gn  = n0 + row;
            if (gn >= N) gn = 0;               // clamp: rows >= N never written back
            gload_lds16(A + (size_t)gn * K + kt + us * 8, As + (p * 256 + tid) * 8);
        }
#pragma unroll
        for (int p = 0; p < 4; ++p) {
            int row = p * 32 + r0;
            gload_lds16(Wt + (size_t)(col0 + row) * K + kt + us * 8, Bs + (p * 256 + tid) * 8);
        }
        __syncthreads();                        // drains vmcnt(0) -> tiles ready
#pragma unroll
        for (int kk = 0; kk < BK; kk += 32) {
            const int sw = (lq + (kk >> 3)) ^ (l15 & 7);   // read-side swizzle
            half8 af0 = *(const half8*)(As + (wave * 32 + l15) * BK + sw * 8);
            half8 af1 = *(const half8*)(As + (wave * 32 + 16 + l15) * BK + sw * 8);
#pragma unroll
            for (int nt = 0; nt < 8; ++nt) {
                half8 bf = *(const half8*)(Bs + (nt * 16 + l15) * BK + sw * 8);
                // swapped operands: D[i=col][j=node], j = lane&15, i = lq*4+reg
                acc[0][nt] = __builtin_amdgcn_mfma_f32_16x16x32_f16(bf, af0, acc[0][nt], 0, 0, 0);
                acc[1][nt] = __builtin_amdgcn_mfma_f32_16x16x32_f16(bf, af1, acc[1][nt], 0, 0, 0);
            }
        }
        __syncthreads();
    }
    // epilogue: per lane, node-row = l15-block, 4 consecutive cols in regs
#pragma unroll
    for (int mi = 0; mi < 2; ++mi) {
        int row = n0 + wave * 32 + mi * 16 + l15;
        if (row < N) {
#pragma unroll
            for (int nt = 0; nt < 8; ++nt) {
                int col = col0 + nt * 16 + lq * 4;
                float4v bv = *(const float4v*)(bias + col);
                half4 hv;
#pragma unroll
                for (int r2 = 0; r2 < 4; ++r2)
                    hv[r2] = (_Float16)(acc[mi][nt][r2] + bv[r2]);
                *(half4*)(out + (size_t)row * COUT + col) = hv;
            }
        }
    }
}

// ---------------------------------------------------------------------------
// GATv2 gather (H=4): wave per node, 4-edge slots, unroll 2 (proven 301.6µs
// form). leaky_relu(v) == fmaxf(v, 0.2v). NO max-subtraction. DPP red16.
// ---------------------------------------------------------------------------
template<typename TOUT>
__global__ __launch_bounds__(256)
void gat_gather4(const _Float16* __restrict__ xl, const _Float16* __restrict__ xr,
                 const int* __restrict__ row_start, const int* __restrict__ esrc,
                 const float* __restrict__ att, const float* __restrict__ gbias,
                 const float* __restrict__ bnp, TOUT* __restrict__ out) {
    constexpr int HC = 256, PER = 4;
    int node = (blockIdx.x * blockDim.x + threadIdx.x) >> 6;
    int lane = threadIdx.x & 63;
    if (node >= N_NODES) return;
    const int base = lane * PER;

    float rr[PER], av[PER], acc[PER];
    {
        half4 rv = *(const half4*)(xr + (size_t)node * HC + base);
#pragma unroll
        for (int k = 0; k < PER; ++k) rr[k] = (float)rv[k];
        *(float4v*)av = *(const float4v*)(att + base);
    }
#pragma unroll
    for (int k = 0; k < PER; ++k) acc[k] = 0.f;

    float l = 0.f;
    const int j0 = row_start[node], j1 = row_start[node + 1];
    for (int jc = j0; jc < j1; jc += 64) {
        int nedge = min(64, j1 - jc);
        int ev = (jc + lane < j1) ? esrc[jc + lane] : 0;
#pragma unroll 2
        for (int jj = 0; jj < nedge; jj += 4) {
            int s[4];
            bool val[4];
#pragma unroll
            for (int u = 0; u < 4; ++u) {
                int idx = jj + u;
                val[u] = idx < nedge;
                s[u] = __shfl(ev, val[u] ? idx : jj, 64);
            }
            float xs[4][PER];
#pragma unroll
            for (int u = 0; u < 4; ++u) {
                half4 xv = *(const half4*)(xl + (size_t)s[u] * HC + base);
#pragma unroll
                for (int k = 0; k < PER; ++k) xs[u][k] = (float)xv[k];
            }
            float pz[4];
#pragma unroll
            for (int u = 0; u < 4; ++u) {
                float pp = 0.f;
#pragma unroll
                for (int k = 0; k < PER; ++k) {
                    float v = xs[u][k] + rr[k];
                    v = fmaxf(v, 0.2f * v);    // leaky_relu, branch-free
                    pp = fmaf(v, av[k], pp);
                }
                pz[u] = red16(pp);             // DPP butterfly within 16 lanes
            }
            float w[4];
#pragma unroll
            for (int u = 0; u < 4; ++u) w[u] = val[u] ? __expf(pz[u]) : 0.f;
            l += (w[0] + w[1]) + (w[2] + w[3]);
#pragma unroll
            for (int k = 0; k < PER; ++k)
                acc[k] += fmaf(w[0], xs[0][k],
                          fmaf(w[1], xs[1][k],
                          fmaf(w[2], xs[2][k], w[3] * xs[3][k])));
        }
    }
    float inv = 1.f / (l + 1e-16f);
    float o[PER];
#pragma unroll
    for (int k = 0; k < PER; ++k) {
        float v = fmaf(acc[k], inv, gbias[base + k]);
        float g  = bnp[base + k], be = bnp[HC + base + k];
        float mm = bnp[2 * HC + base + k], va = bnp[3 * HC + base + k];
        v = g * (v - mm) * rsqrtf(va + 1e-5f) + be;
        o[k] = (v > 0.f) ? v : (__expf(v) - 1.f);
    }
    half4 ov;
#pragma unroll
    for (int k = 0; k < PER; ++k) ov[k] = (_Float16)o[k];
    *(half4*)((_Float16*)out + (size_t)node * HC + base) = ov;
}

// ---------------------------------------------------------------------------
// GATv2 gather (H=1, C=128): DUAL-EDGE wave + unroll 2 (proven form).
// Two 32-lane halves, 4 ch/lane each, own edge per half -> 2 edges per slot.
// Reduction: xor-16 shuffle + 4 DPP hops. Halves combined once per node.
// ---------------------------------------------------------------------------
__global__ __launch_bounds__(256)
void gat_gather1(const _Float16* __restrict__ xl, const _Float16* __restrict__ xr,
                 const int* __restrict__ row_start, const int* __restrict__ esrc,
                 const float* __restrict__ att, const float* __restrict__ gbias,
                 const float* __restrict__ bnp, float* __restrict__ out) {
    constexpr int HC = 128, PER = 4;
    int node = (blockIdx.x * blockDim.x + threadIdx.x) >> 6;
    int lane = threadIdx.x & 63;
    if (node >= N_NODES) return;
    const int half = lane >> 5;
    const int base = (lane & 31) * PER;

    float rr[PER], av[PER], acc[PER];
    {
        half4 rv = *(const half4*)(xr + (size_t)node * HC + base);
#pragma unroll
        for (int k = 0; k < PER; ++k) rr[k] = (float)rv[k];
        *(float4v*)av = *(const float4v*)(att + base);
    }
#pragma unroll
    for (int k = 0; k < PER; ++k) acc[k] = 0.f;

    float l = 0.f;
    const int j0 = row_start[node], j1 = row_start[node + 1];
    for (int jc = j0; jc < j1; jc += 64) {
        int nedge = min(64, j1 - jc);
        int ev = (jc + lane < j1) ? esrc[jc + lane] : 0;
#pragma unroll 2
        for (int jj = 0; jj < nedge; jj += 8) {          // 8 edges: 4 per half
            int s[4];
            bool val[4];
#pragma unroll
            for (int u = 0; u < 4; ++u) {
                int idx = jj + 2 * u + half;
                val[u] = idx < nedge;
                s[u] = __shfl(ev, val[u] ? idx : jj, 64);
            }
            float xs[4][PER];
#pragma unroll
            for (int u = 0; u < 4; ++u) {
                half4 xv = *(const half4*)(xl + (size_t)s[u] * HC + base);
#pragma unroll
                for (int k = 0; k < PER; ++k) xs[u][k] = (float)xv[k];
            }
            float pz[4];
#pragma unroll
            for (int u = 0; u < 4; ++u) {
                float pp = 0.f;
#pragma unroll
                for (int k = 0; k < PER; ++k) {
                    float v = xs[u][k] + rr[k];
                    v = fmaxf(v, 0.2f * v);    // leaky_relu, branch-free
                    pp = fmaf(v, av[k], pp);
                }
                pp += __shfl_xor(pp, 16, 64);            // cross-row, in-half
                pz[u] = red16(pp);                       // 4 DPP hops
            }
            float w[4];
#pragma unroll
            for (int u = 0; u < 4; ++u) w[u] = val[u] ? __expf(pz[u]) : 0.f;
            l += (w[0] + w[1]) + (w[2] + w[3]);
#pragma unroll
            for (int k = 0; k < PER; ++k)
                acc[k] += fmaf(w[0], xs[0][k],
                          fmaf(w[1], xs[1][k],
                          fmaf(w[2], xs[2][k], w[3] * xs[3][k])));
        }
    }
    // combine the two halves (disjoint edge sets, same channels)
    l += __shfl_xor(l, 32, 64);
#pragma unroll
    for (int k = 0; k < PER; ++k) acc[k] += __shfl_xor(acc[k], 32, 64);

    if (half == 0) {
        float inv = 1.f / (l + 1e-16f);
        float o[PER];
#pragma unroll
        for (int k = 0; k < PER; ++k) {
            float v = fmaf(acc[k], inv, gbias[base + k]);
            float g  = bnp[base + k], be = bnp[HC + base + k];
            float mm = bnp[2 * HC + base + k], va = bnp[3 * HC + base + k];
            v = g * (v - mm) * rsqrtf(va + 1e-5f) + be;
            o[k] = (v > 0.f) ? v : (__expf(v) - 1.f);
        }
        *(float4v*)(out + (size_t)node * HC + base) = *(float4v*)o;
    }
}

// ---------------------------------------------------------------------------
// K9: fused pooling + classifier, one block (512 threads) per graph.
// float4 node loop (32 threads span a 512B row, 16-way node split).
// ---------------------------------------------------------------------------
__global__ __launch_bounds__(512)
void pool_cls(const float* __restrict__ h, const int* __restrict__ gstart,
              const float* __restrict__ w1, const float* __restrict__ b1,
              const float* __restrict__ bnp,
              const float* __restrict__ w2, const float* __restrict__ b2,
              const float* __restrict__ w3, const float* __restrict__ b3,
              float* __restrict__ out) {
    __shared__ float4v part4[512];             // 8KB: pooling partials
    __shared__ float sg[256];
    __shared__ float sz1[128];
    __shared__ float sz2[64];
    __shared__ float sz3[2];
    float* part = (float*)part4;               // alias for GEMV partials
    int g = blockIdx.x, t = threadIdx.x;
    int a = gstart[g], b = gstart[g + 1];

    // --- mean+max pooling: cq = channel quad (0..31), q16 = node slice
    int cq = t & 31, q16 = t >> 5;             // q16 in 0..15
    float4v sum = {0.f, 0.f, 0.f, 0.f};
    float4v mx  = {-INFINITY, -INFINITY, -INFINITY, -INFINITY};
    for (int i = a + q16; i < b; i += 16) {
        float4v v = *(const float4v*)(h + (size_t)i * 128 + cq * 4);
#pragma unroll
        for (int k = 0; k < 4; ++k) { sum[k] += v[k]; mx[k] = fmaxf(mx[k], v[k]); }
    }
    part4[t] = sum;
    __syncthreads();
    if (t < 32) {
        float4v s = part4[t];
        for (int r = 1; r < 16; ++r) {
            float4v p = part4[r * 32 + t];
#pragma unroll
            for (int k = 0; k < 4; ++k) s[k] += p[k];
        }
        float inv = 1.f / fmaxf((float)(b - a), 1.f);
#pragma unroll
        for (int k = 0; k < 4; ++k) sg[t * 4 + k] = s[k] * inv;
    }
    __syncthreads();
    part4[t] = mx;
    __syncthreads();
    if (t < 32) {
        float4v m = part4[t];
        for (int r = 1; r < 16; ++r) {
            float4v p = part4[r * 32 + t];
#pragma unroll
            for (int k = 0; k < 4; ++k) m[k] = fmaxf(m[k], p[k]);
        }
#pragma unroll
        for (int k = 0; k < 4; ++k) sg[128 + t * 4 + k] = (b > a) ? m[k] : 0.f;
    }
    __syncthreads();

    // --- classifier GEMV chain (proven 512-thread split)
    int c = t & 127, q = t >> 7;               // q in 0..3
    float acc = 0.f;
    for (int i = q * 64; i < q * 64 + 64; ++i) acc += sg[i] * w1[i * 128 + c];
    part[t] = acc;
    __syncthreads();
    if (q == 0) {
        float z = part[c] + part[c + 128] + part[c + 256] + part[c + 384] + b1[c];
        float ga = bnp[c], be = bnp[128 + c], m = bnp[256 + c], va = bnp[384 + c];
        z = ga * (z - m) * rsqrtf(va + 1e-5f) + be;
        sz1[c] = fmaxf(z, 0.f);
    }
    __syncthreads();
    if (t < 128) {
        int o = t & 63, q2 = t >> 6;
        float a2 = 0.f;
        for (int i = q2 * 64; i < q2 * 64 + 64; ++i) a2 += sz1[i] * w2[i * 64 + o];
        part[t] = a2;
    }
    __syncthreads();
    if (t < 64) sz2[t] = fmaxf(part[t] + part[t + 64] + b2[t], 0.f);
    __syncthreads();
    if (t < 2) {
        float a3 = b3[t];
        for (int i = 0; i < 64; ++i) a3 += sz2[i] * w3[i * 2 + t];
        sz3[t] = a3;
    }
    __syncthreads();
    if (t < 2) {
        float mm = fmaxf(sz3[0], sz3[1]);
        float lse = mm + logf(expf(sz3[0] - mm) + expf(sz3[1] - mm));
        out[g * 2 + t] = sz3[t] - lse;
    }
}

// ---------------------------------------------------------------------------
// launch: 1 memset + 9 kernels
// ---------------------------------------------------------------------------
extern "C" void kernel_launch(void* const* d_in, const int* in_sizes, int n_in,
                              void* d_out, int out_size, void* d_ws, size_t ws_size,
                              hipStream_t stream) {
    const float* x       = (const float*)d_in[0];
    const int*   ei      = (const int*)d_in[1];
    const int*   batch   = (const int*)d_in[2];
    const float* w_in    = (const float*)d_in[3];
    const float* b_in    = (const float*)d_in[4];
    const float* bn_in   = (const float*)d_in[5];
    const float* g1_wl   = (const float*)d_in[6];
    const float* g1_bl   = (const float*)d_in[7];
    const float* g1_wr   = (const float*)d_in[8];
    const float* g1_br   = (const float*)d_in[9];
    const float* g1_att  = (const float*)d_in[10];
    const float* g1_bias = (const float*)d_in[11];
    const float* bn1     = (const float*)d_in[12];
    const float* g2_wl   = (const float*)d_in[13];
    const float* g2_bl   = (const float*)d_in[14];
    const float* g2_wr   = (const float*)d_in[15];
    const float* g2_br   = (const float*)d_in[16];
    const float* g2_att  = (const float*)d_in[17];
    const float* g2_bias = (const float*)d_in[18];
    const float* bn2     = (const float*)d_in[19];
    const float* g3_wl   = (const float*)d_in[20];
    const float* g3_bl   = (const float*)d_in[21];
    const float* g3_wr   = (const float*)d_in[22];
    const float* g3_br   = (const float*)d_in[23];
    const float* g3_att  = (const float*)d_in[24];
    const float* g3_bias = (const float*)d_in[25];
    const float* bn3     = (const float*)d_in[26];
    const float* c_w1    = (const float*)d_in[27];
    const float* c_b1    = (const float*)d_in[28];
    const float* c_bn    = (const float*)d_in[29];
    const float* c_w2    = (const float*)d_in[30];
    const float* c_b2    = (const float*)d_in[31];
    const float* c_w3    = (const float*)d_in[32];
    const float* c_b3    = (const float*)d_in[33];
    float* out = (float*)d_out;

    // ---- workspace layout
    const size_t NHC = (size_t)N_NODES * 256;
    _Float16* a16  = (_Float16*)d_ws;
    _Float16* xl16 = a16 + NHC;
    _Float16* xr16 = xl16 + NHC;
    _Float16* wt = xr16 + NHC;
    _Float16* wt1l = wt;            _Float16* wt1r = wt + 16384;
    _Float16* wt2l = wt + 32768;    _Float16* wt2r = wt + 98304;
    _Float16* wt3l = wt + 163840;   _Float16* wt3r = wt + 196608;
    float* fbase = (float*)(wt + 262144);
    float* bufD = fbase;
    int* iw = (int*)(bufD + (size_t)N_NODES * 128);
    int* deg       = iw;            int* cnt    = iw + 30000;   // contiguous pair
    int* row_start = iw + 90128;
    int* esrc      = iw + 120129;
    int* gstart    = iw + 390429;

    const int BT = 256;
    const int NT128 = cdiv(N_NODES, 128);      // 235

    // N0: zero deg+cnt
    hipMemsetAsync(deg, 0, 60000 * sizeof(int), stream);

    // K1: histogram + w1 transpose + input layer
    hist_wprep_input<<<1024, BT, 0, stream>>>(ei, deg, x, w_in, b_in, bn_in, a16,
                                              g1_wl, g1_wr, wt1l, wt1r);
    // K2: row_start scan + gstart binary search
    scan_all<<<NCH, 256, 0, stream>>>(deg, batch, row_start, gstart);

    // K3: GAT layer-1 GEMM + fused CSR scatter + deferred wt2/wt3 transposes
    gemm_mfma<64, 256, 1><<<NT128 * 4 + NT128, 256, 0, stream>>>(
        a16, wt1l, g1_bl, wt1r, g1_br, xl16, xr16, ei, row_start, cnt, esrc, N_NODES,
        g2_wl, g2_wr, g3_wl, g3_wr, wt2l, wt2r, wt3l, wt3r);
    // K4: gather 1
    gat_gather4<_Float16><<<cdiv(N_NODES * 64, BT), BT, 0, stream>>>(
        xl16, xr16, row_start, esrc, g1_att, g1_bias, bn1, a16);

    // K5/K6: GAT layer 2
    gemm_mfma<256, 256, 0><<<NT128 * 4, 256, 0, stream>>>(
        a16, wt2l, g2_bl, wt2r, g2_br, xl16, xr16, nullptr, nullptr, nullptr, nullptr, N_NODES,
        nullptr, nullptr, nullptr, nullptr, nullptr, nullptr, nullptr, nullptr);
    gat_gather4<_Float16><<<cdiv(N_NODES * 64, BT), BT, 0, stream>>>(
        xl16, xr16, row_start, esrc, g2_att, g2_bias, bn2, a16);

    // K7/K8: GAT layer 3 (dual-edge gather emits f32 for pooling)
    gemm_mfma<256, 128, 0><<<NT128 * 2, 256, 0, stream>>>(
        a16, wt3l, g3_bl, wt3r, g3_br, xl16, xr16, nullptr, nullptr, nullptr, nullptr, N_NODES,
        nullptr, nullptr, nullptr, nullptr, nullptr, nullptr, nullptr, nullptr);
    gat_gather1<<<cdiv(N_NODES * 64, BT), BT, 0, stream>>>(
        xl16, xr16, row_start, esrc, g3_att, g3_bias, bn3, bufD);

    // K9: fused pooling + classifier
    pool_cls<<<N_GRAPHS, 512, 0, stream>>>(bufD, gstart, c_w1, c_b1, c_bn,
                                           c_w2, c_b2, c_w3, c_b3, out);
}